// Round 7
// baseline (444.390 us; speedup 1.0000x reference)
//
#include <hip/hip_runtime.h>

#define BS 8
#define LQ 900
#define NH 8
#define NL 4
#define NP 4
#define HD 32
#define ED 256
#define LEN_V 21760
#define QC 8          // queries per sample block
#define NQC 113       // ceil(900/8)

typedef __attribute__((ext_vector_type(8))) short bf16x8;
typedef __attribute__((ext_vector_type(4))) float f32x4;
typedef __attribute__((ext_vector_type(4))) float fv4;

static __device__ __forceinline__ unsigned short f2bf(float f) {
  union { float f; unsigned u; } x; x.f = f;
  unsigned r = x.u + 0x7fffu + ((x.u >> 16) & 1u);
  return (unsigned short)(r >> 16);
}
static __device__ __forceinline__ float bf_lo(unsigned u) {
  union { unsigned u; float f; } x; x.u = u << 16;
  return x.f;
}
static __device__ __forceinline__ float bf_hi(unsigned u) {
  union { unsigned u; float f; } x; x.u = u & 0xffff0000u;
  return x.f;
}
static __device__ __forceinline__ unsigned pack2(float a, float b) {
  return (unsigned)f2bf(a) | ((unsigned)f2bf(b) << 16);
}

// ---------------------------------------------------------------------------
// K0: pre-swizzle w_value into bf16 B-fragment chunks.
// ---------------------------------------------------------------------------
__global__ __launch_bounds__(256) void bprep_kernel(
    const float* __restrict__ w, unsigned short* __restrict__ Bsw) {
  const int id = blockIdx.x * 256 + threadIdx.x;
  const int n = id & 255;
  const int kseg = (id >> 8) & 3;
  const int kc = id >> 10;
  const float* src = &w[(kc * 32 + kseg * 8) * 256 + n];
  float f[8];
#pragma unroll
  for (int j = 0; j < 8; j++) f[j] = src[j * 256];
  uint4 pk;
  pk.x = pack2(f[0], f[1]);
  pk.y = pack2(f[2], f[3]);
  pk.z = pack2(f[4], f[5]);
  pk.w = pack2(f[6], f[7]);
  *(uint4*)&Bsw[((kc * 4 + kseg) * 256 + n) * 8] = pk;
}

// ---------------------------------------------------------------------------
// K1: v = value @ w_value + b_value (bf16 MFMA), A via double-buffered LDS,
// B direct from pre-swizzled Bsw. (unchanged from round 6)
// ---------------------------------------------------------------------------
__global__ __launch_bounds__(256, 4) void vproj_kernel(
    const float* __restrict__ value, const unsigned short* __restrict__ Bsw,
    const float* __restrict__ bias, unsigned short* __restrict__ vout) {
  const int t = threadIdx.x;
  const int row0 = blockIdx.x * 64;
  const int wv = t >> 6;
  const int lane = t & 63;
  const int quad = lane >> 4;
  const int nn = lane & 15;

  __shared__ unsigned short a_lds[2][4 * 64 * 8];

  f32x4 acc[4][4];
#pragma unroll
  for (int i = 0; i < 4; i++)
#pragma unroll
    for (int j = 0; j < 4; j++) acc[i][j] = (f32x4)(0.f);

  const int arow = t >> 2;
  const int akseg = t & 3;
  const int aslot = (akseg * 64 + arow) * 8;
  const unsigned short* bptr = &Bsw[(quad * 256 + wv * 64 + nn) * 8];
  const float* abase = &value[(row0 + arow) * 256 + akseg * 8];

  {
    fv4 v0 = __builtin_nontemporal_load((const fv4*)abase);
    fv4 v1 = __builtin_nontemporal_load((const fv4*)(abase + 4));
    uint4 pk;
    pk.x = pack2(v0.x, v0.y);
    pk.y = pack2(v0.z, v0.w);
    pk.z = pack2(v1.x, v1.y);
    pk.w = pack2(v1.z, v1.w);
    *(uint4*)&a_lds[0][aslot] = pk;
  }

  for (int kc = 0; kc < 8; kc++) {
    __syncthreads();
    fv4 n0, n1;
    if (kc < 7) {
      const float* pa = abase + (kc + 1) * 32;
      n0 = __builtin_nontemporal_load((const fv4*)pa);
      n1 = __builtin_nontemporal_load((const fv4*)(pa + 4));
    }
    bf16x8 af[4], bfr[4];
#pragma unroll
    for (int ct = 0; ct < 4; ct++)
      bfr[ct] = *(const bf16x8*)(bptr + (kc * 1024 + ct * 16) * 8);
    const unsigned short* cur = &a_lds[kc & 1][0];
#pragma unroll
    for (int rt = 0; rt < 4; rt++)
      af[rt] = *(const bf16x8*)&cur[(quad * 64 + rt * 16 + nn) * 8];
#pragma unroll
    for (int rt = 0; rt < 4; rt++)
#pragma unroll
      for (int ct = 0; ct < 4; ct++)
        acc[rt][ct] = __builtin_amdgcn_mfma_f32_16x16x32_bf16(
            af[rt], bfr[ct], acc[rt][ct], 0, 0, 0);
    if (kc < 7) {
      uint4 pk;
      pk.x = pack2(n0.x, n0.y);
      pk.y = pack2(n0.z, n0.w);
      pk.z = pack2(n1.x, n1.y);
      pk.w = pack2(n1.z, n1.w);
      *(uint4*)&a_lds[(kc + 1) & 1][aslot] = pk;
    }
  }

  const int bb = row0 / LEN_V;
  const int s0 = row0 - bb * LEN_V;
#pragma unroll
  for (int ct = 0; ct < 4; ct++) {
    const int col = wv * 64 + ct * 16 + nn;
    const float bv = bias[col];
    const int h = col >> 5;
    const int d = col & 31;
    unsigned short* vb = &vout[((bb * NH + h) * LEN_V + s0) * HD + d];
#pragma unroll
    for (int rt = 0; rt < 4; rt++) {
      f32x4 f = acc[rt][ct];
#pragma unroll
      for (int reg = 0; reg < 4; reg++) {
        const int s = rt * 16 + quad * 4 + reg;
        vb[s * HD] = f2bf(f[reg] + bv);
      }
    }
  }
}

// ---------------------------------------------------------------------------
// K2: OFF/LOG projections fused, N=384. (unchanged)
// ---------------------------------------------------------------------------
__global__ __launch_bounds__(384, 2) void offattn_kernel(
    const float* __restrict__ query,
    const float* __restrict__ w_off, const float* __restrict__ b_off,
    const float* __restrict__ w_attn, const float* __restrict__ b_attn,
    float* __restrict__ OFF, float* __restrict__ LOG) {
  const int t = threadIdx.x;
  const int row0 = blockIdx.x * 32;
  const int rg = t / 96;
  const int c4 = t % 96;
  const int col = c4 * 4;
  const bool isOff = col < 256;
  const float* wbase = isOff ? (w_off + col) : (w_attn + (col - 256));
  const int wstride = isOff ? 256 : 128;
  const float* bb = isOff ? (b_off + col) : (b_attn + (col - 256));
  __shared__ float a_lds[32][8];

  float4 acc[8];
#pragma unroll
  for (int r = 0; r < 8; r++) acc[r] = make_float4(0.f, 0.f, 0.f, 0.f);

  for (int k0 = 0; k0 < 256; k0 += 8) {
    __syncthreads();
    if (t < 256) a_lds[t >> 3][t & 7] = query[(row0 + (t >> 3)) * 256 + k0 + (t & 7)];
    __syncthreads();
    float4 wr[8];
#pragma unroll
    for (int k = 0; k < 8; k++)
      wr[k] = *(const float4*)&wbase[(k0 + k) * wstride];
#pragma unroll
    for (int r = 0; r < 8; r++) {
      const float* ar = &a_lds[rg * 8 + r][0];
      float4 a0 = *(const float4*)&ar[0];
      float4 a1 = *(const float4*)&ar[4];
      float4 s = acc[r];
      s.x += a0.x*wr[0].x + a0.y*wr[1].x + a0.z*wr[2].x + a0.w*wr[3].x
           + a1.x*wr[4].x + a1.y*wr[5].x + a1.z*wr[6].x + a1.w*wr[7].x;
      s.y += a0.x*wr[0].y + a0.y*wr[1].y + a0.z*wr[2].y + a0.w*wr[3].y
           + a1.x*wr[4].y + a1.y*wr[5].y + a1.z*wr[6].y + a1.w*wr[7].y;
      s.z += a0.x*wr[0].z + a0.y*wr[1].z + a0.z*wr[2].z + a0.w*wr[3].z
           + a1.x*wr[4].z + a1.y*wr[5].z + a1.z*wr[6].z + a1.w*wr[7].z;
      s.w += a0.x*wr[0].w + a0.y*wr[1].w + a0.z*wr[2].w + a0.w*wr[3].w
           + a1.x*wr[4].w + a1.y*wr[5].w + a1.z*wr[6].w + a1.w*wr[7].w;
      acc[r] = s;
    }
  }

  const float4 bv = *(const float4*)bb;
#pragma unroll
  for (int r = 0; r < 8; r++) {
    const int grow = row0 + rg * 8 + r;
    float4 o = make_float4(acc[r].x + bv.x, acc[r].y + bv.y,
                           acc[r].z + bv.z, acc[r].w + bv.w);
    if (isOff) *(float4*)&OFF[grow * 256 + col] = o;
    else       *(float4*)&LOG[grow * 128 + (col - 256)] = o;
  }
}

// ---------------------------------------------------------------------------
// K3: sampling, L2-locality restructure. Block = (b, h, 8 queries), 128 thr.
// blockIdx = b*(NQC*8) + qc*8 + h  =>  XCD = h (round-robin heuristic); all
// q-chunks of one (b,h) run consecutively on one XCD; gather working set =
// 1.4 MB head-slice, L2-resident.
// ---------------------------------------------------------------------------
__global__ __launch_bounds__(128, 8) void sample_kernel(
    const float* __restrict__ refp, const unsigned short* __restrict__ vp,
    const float* __restrict__ OFF, const float* __restrict__ LOG,
    float* __restrict__ RES) {
  const int t = threadIdx.x;
  const int h = blockIdx.x & 7;
  const int r_ = blockIdx.x >> 3;
  const int qc = r_ % NQC;
  const int b = r_ / NQC;
  const int q0 = qc * QC;
  const int nq = min(QC, LQ - q0);

  __shared__ float off_s[QC][32];
  __shared__ float log_s[QC][16];
  __shared__ float ref_s[QC][4][2];
  __shared__ int scw[256][4];   // [(lp*8+q)*2+cp] -> (o0, w0, o1, w1)

  // ---- phase A: this head's offsets/logits/refs ----
#pragma unroll
  for (int j = 0; j < 2; j++) {
    const int q = j * 4 + (t >> 5);
    if (q < nq)
      off_s[q][t & 31] = OFF[(b * LQ + q0 + q) * 256 + h * 32 + (t & 31)];
  }
  {
    const int q = t >> 4;
    if (q < nq)
      log_s[q][t & 15] = LOG[(b * LQ + q0 + q) * 128 + h * 16 + (t & 15)];
  }
  if (t < 64) {
    const int q = t >> 3, l = (t >> 1) & 3, xy = t & 1;
    if (q < nq)
      ref_s[q][l][xy] = refp[((b * LQ + q0 + q) * NL + l) * 2 + xy];
  }
  __syncthreads();

  // ---- softmax per q over 16 ----
  if (t < nq) {
    float* a = &log_s[t][0];
    float m = a[0];
#pragma unroll
    for (int i = 1; i < 16; i++) m = fmaxf(m, a[i]);
    float e[16];
    float ssum = 0.f;
#pragma unroll
    for (int i = 0; i < 16; i++) { e[i] = __expf(a[i] - m); ssum += e[i]; }
    const float inv = 1.f / ssum;
#pragma unroll
    for (int i = 0; i < 16; i++) a[i] = e[i] * inv;
  }
  __syncthreads();

  // ---- phase B: one set per thread -> 2 corner-pair records ----
  {
    const int q = t >> 4;
    const int lp = t & 15;
    if (q < nq) {
      const int l = lp >> 2, p = lp & 3;
      const int W = 128 >> l;
      const int base = (l == 0) ? 0 : ((l == 1) ? 16384 : ((l == 2) ? 20480 : 21504));
      const float Wf = (float)W;
      const float px = ref_s[q][l][0] * Wf + off_s[q][l * 8 + p * 2 + 0] - 0.5f;
      const float py = ref_s[q][l][1] * Wf + off_s[q][l * 8 + p * 2 + 1] - 0.5f;
      const float aw = log_s[q][lp];
      const float x0f = floorf(px), y0f = floorf(py);
      const float dx = px - x0f, dy = py - y0f;
      const int x0 = (int)x0f, y0 = (int)y0f;
      const int x1 = x0 + 1, y1 = y0 + 1;
      const float mx0 = (x0 >= 0 && x0 < W) ? 1.f : 0.f;
      const float mx1 = (x1 >= 0 && x1 < W) ? 1.f : 0.f;
      const float my0 = (y0 >= 0 && y0 < W) ? 1.f : 0.f;
      const float my1 = (y1 >= 0 && y1 < W) ? 1.f : 0.f;
      const int x0c = min(max(x0, 0), W - 1);
      const int x1c = min(max(x1, 0), W - 1);
      const int y0c = min(max(y0, 0), W - 1);
      const int y1c = min(max(y1, 0), W - 1);
      const float w00 = (1.f - dx) * (1.f - dy) * mx0 * my0 * aw;
      const float w10 = dx * (1.f - dy) * mx1 * my0 * aw;
      const float w01 = (1.f - dx) * dy * mx0 * my1 * aw;
      const float w11 = dx * dy * mx1 * my1 * aw;
      const int slot = (lp * 8 + q) * 2;
      int4 recA, recB;                     // offsets in uint4 (16B) units
      recA.x = (base + y0c * W + x0c) * 4; recA.y = __float_as_int(w00);
      recA.z = (base + y0c * W + x1c) * 4; recA.w = __float_as_int(w10);
      recB.x = (base + y1c * W + x0c) * 4; recB.y = __float_as_int(w01);
      recB.z = (base + y1c * W + x1c) * 4; recB.w = __float_as_int(w11);
      *(int4*)&scw[slot + 0][0] = recA;
      *(int4*)&scw[slot + 1][0] = recB;
    }
  }
  __syncthreads();

  // ---- phase C: thread = (q, d8, cp, lpH) ----
  const int q = t >> 4;
  const int d8 = (t >> 2) & 3;
  const int cp = (t >> 1) & 1;
  const int lpH = t & 1;
  const uint4* vpu = (const uint4*)vp + (size_t)(b * NH + h) * (LEN_V * HD / 8);
  float r[8];
#pragma unroll
  for (int j = 0; j < 8; j++) r[j] = 0.f;
  if (q < nq) {
#pragma unroll
    for (int i = 0; i < 8; i++) {
      const int lp = lpH * 8 + i;
      const int4 rec = *(const int4*)&scw[(lp * 8 + q) * 2 + cp][0];
      const uint4 ua = vpu[rec.x + d8];
      const uint4 ub = vpu[rec.z + d8];
      const float wa = __int_as_float(rec.y);
      const float wb = __int_as_float(rec.w);
      r[0] += wa * bf_lo(ua.x) + wb * bf_lo(ub.x);
      r[1] += wa * bf_hi(ua.x) + wb * bf_hi(ub.x);
      r[2] += wa * bf_lo(ua.y) + wb * bf_lo(ub.y);
      r[3] += wa * bf_hi(ua.y) + wb * bf_hi(ub.y);
      r[4] += wa * bf_lo(ua.z) + wb * bf_lo(ub.z);
      r[5] += wa * bf_hi(ua.z) + wb * bf_hi(ub.z);
      r[6] += wa * bf_lo(ua.w) + wb * bf_lo(ub.w);
      r[7] += wa * bf_hi(ua.w) + wb * bf_hi(ub.w);
    }
  }
  // reduce over lpH (xor 1) then cp (xor 2)
#pragma unroll
  for (int j = 0; j < 8; j++) {
    r[j] += __shfl_xor(r[j], 1);
    r[j] += __shfl_xor(r[j], 2);
  }
  // each of the 4 lanes in a (q,d8) group writes 2 dims -> contiguous
  if (q < nq) {
    const int sub = cp * 2 + lpH;
    float2 o = make_float2(r[sub * 2], r[sub * 2 + 1]);
    *(float2*)&RES[(b * LQ + q0 + q) * 256 + h * 32 + d8 * 8 + sub * 2] = o;
  }
}

// ---------------------------------------------------------------------------
// K4: out = RES @ w_out + b_out. (unchanged)
// ---------------------------------------------------------------------------
__global__ __launch_bounds__(256, 2) void outproj_kernel(
    const float* __restrict__ RES, const float* __restrict__ w,
    const float* __restrict__ bias, float* __restrict__ out) {
  const int t = threadIdx.x;
  const int row0 = blockIdx.x * 32;
  const int rg = t >> 6;
  const int c0 = (t & 63) << 2;
  __shared__ float a_lds[32][8];

  float4 acc[8];
#pragma unroll
  for (int r = 0; r < 8; r++) acc[r] = make_float4(0.f, 0.f, 0.f, 0.f);

  const int lr = t >> 3;
  const int lk = t & 7;
  for (int k0 = 0; k0 < 256; k0 += 8) {
    __syncthreads();
    a_lds[lr][lk] = RES[(row0 + lr) * 256 + k0 + lk];
    __syncthreads();
    float4 wr[8];
#pragma unroll
    for (int k = 0; k < 8; k++)
      wr[k] = *(const float4*)&w[(k0 + k) * 256 + c0];
#pragma unroll
    for (int r = 0; r < 8; r++) {
      const float* ar = &a_lds[rg * 8 + r][0];
      float4 a0 = *(const float4*)&ar[0];
      float4 a1 = *(const float4*)&ar[4];
      float4 s = acc[r];
      s.x += a0.x*wr[0].x + a0.y*wr[1].x + a0.z*wr[2].x + a0.w*wr[3].x
           + a1.x*wr[4].x + a1.y*wr[5].x + a1.z*wr[6].x + a1.w*wr[7].x;
      s.y += a0.x*wr[0].y + a0.y*wr[1].y + a0.z*wr[2].y + a0.w*wr[3].y
           + a1.x*wr[4].y + a1.y*wr[5].y + a1.z*wr[6].y + a1.w*wr[7].y;
      s.z += a0.x*wr[0].z + a0.y*wr[1].z + a0.z*wr[2].z + a0.w*wr[3].z
           + a1.x*wr[4].z + a1.y*wr[5].z + a1.z*wr[6].z + a1.w*wr[7].z;
      s.w += a0.x*wr[0].w + a0.y*wr[1].w + a0.z*wr[2].w + a0.w*wr[3].w
           + a1.x*wr[4].w + a1.y*wr[5].w + a1.z*wr[6].w + a1.w*wr[7].w;
      acc[r] = s;
    }
  }

  const float4 bv = *(const float4*)&bias[c0];
#pragma unroll
  for (int r = 0; r < 8; r++) {
    const int grow = row0 + rg * 8 + r;
    float4 o = make_float4(acc[r].x + bv.x, acc[r].y + bv.y,
                           acc[r].z + bv.z, acc[r].w + bv.w);
    *(float4*)&out[grow * 256 + c0] = o;
  }
}

extern "C" void kernel_launch(void* const* d_in, const int* in_sizes, int n_in,
                              void* d_out, int out_size, void* d_ws, size_t ws_size,
                              hipStream_t stream) {
  (void)in_sizes; (void)n_in; (void)out_size; (void)ws_size;
  const float* query   = (const float*)d_in[0];
  const float* refp    = (const float*)d_in[1];
  const float* value   = (const float*)d_in[2];
  const float* w_value = (const float*)d_in[3];
  const float* b_value = (const float*)d_in[4];
  const float* w_off   = (const float*)d_in[5];
  const float* b_off   = (const float*)d_in[6];
  const float* w_attn  = (const float*)d_in[7];
  const float* b_attn  = (const float*)d_in[8];
  const float* w_out   = (const float*)d_in[9];
  const float* b_out   = (const float*)d_in[10];
  float* out = (float*)d_out;

  char* ws = (char*)d_ws;
  unsigned short* vp = (unsigned short*)ws;                 // 89,128,960 B
  float* OFF = (float*)(ws + 89128960);                     // 7,372,800 B
  float* LOG = (float*)(ws + 89128960 + 7372800);           // 3,686,400 B
  float* RES = (float*)(ws + 89128960 + 7372800 + 3686400); // 7,372,800 B
  unsigned short* Bsw = (unsigned short*)(ws + 89128960 + 7372800 + 3686400 + 7372800); // 131,072 B

  bprep_kernel<<<32, 256, 0, stream>>>(w_value, Bsw);
  vproj_kernel<<<(BS * LEN_V) / 64, 256, 0, stream>>>(value, Bsw, b_value, vp);
  offattn_kernel<<<(BS * LQ) / 32, 384, 0, stream>>>(query, w_off, b_off,
                                                     w_attn, b_attn, OFF, LOG);
  sample_kernel<<<BS * NQC * NH, 128, 0, stream>>>(refp, vp, OFF, LOG, RES);
  outproj_kernel<<<(BS * LQ) / 32, 256, 0, stream>>>(RES, w_out, b_out, out);
}